// Round 12
// baseline (902.729 us; speedup 1.0000x reference)
//
#include <hip/hip_runtime.h>
#include <hip/hip_cooperative_groups.h>

namespace cg = cooperative_groups;

#define N_USERS_C 100000
#define N_NODES_C 150000
#define D 64
#define NB 2344              // ceil(150000/64) fine buckets (compact-row space)
#define NSUP 74              // ceil(150000/2048) super buckets
#define CPAD 16              // global cursor padding: 1 int per 64B line
#define TILE1 32             // fuse1 rows per block
#define SPAD 33              // fuse1 transposed-tile row stride (2-way banks, free)
#define SPAD2 17             // fuse2 transposed-tile row stride (2-way)
#define FCAP 1536            // fixed fine-bucket capacity (mean ~1030)
#define S1B 256              // s1 blocks
#define FRAG 240             // per-(block,super) fragment capacity (mean 128, +10 sigma)
#define S2CAP 2560           // s2 per-block staging capacity
#define BPS 16               // blocks per super in s2
#define FPB (S1B / BPS)      // fragments per s2 block = 16
#define MARK 1               // "marked" byte; ws poison is 0xAA so no zeroing needed
#define CB 1024              // front_k cooperative blocks
#define CT 256               // front_k threads per block
#define CHUNK 147            // ceil(150000/1024) elements per front_k block

// ---------------- front_k: mark1+mark2+scan1+scanB fused (cooperative) ----------------
// 4 serial launches -> 1. Phases separated by device-fence + grid.sync:
//   P1: mark sampled nodes (+ bcur init, no dependency)
//   P2: mark 1-hop neighbors (edge pass)
//   P3: per-block 147-elem LDS scan of need flags
//   P4: block 0 scans the 1024 block sums -> bpre, Mptr
//   P5: finalize idx / list from LDS partials kept live across syncs
// No global atomics anywhere (R10 lesson: ~40 us per million random atomics).
__global__ __launch_bounds__(CT) void front_k(
    const int* __restrict__ u, const int* __restrict__ it,
    const int* __restrict__ rows, const int* __restrict__ cols,
    unsigned char* __restrict__ samp, unsigned char* __restrict__ need,
    int* __restrict__ idx, int* __restrict__ list,
    int* __restrict__ bcur, int* __restrict__ Mptr,
    int* __restrict__ bsum, int* __restrict__ bpre,
    int batch, int nnz, int n)
{
    cg::grid_group grid = cg::this_grid();
    __shared__ int sc[CHUNK];
    __shared__ int ts[CT];

    int t   = threadIdx.x;
    int b   = blockIdx.x;
    int tid = b * CT + t;
    const int nth = CB * CT;

    // ---- P1: mark sampled + init fine-bucket cursors ----
    for (int i = tid; i < 2 * batch; i += nth) {
        int nd = (i < batch) ? u[i] : N_USERS_C + it[i - batch];
        samp[nd] = MARK;
        need[nd] = MARK;
    }
    for (int i = tid; i < NB; i += nth) bcur[i * CPAD] = i * FCAP;
    __threadfence();
    grid.sync();

    // ---- P2: mark neighbors of sampled rows ----
    for (int e = tid; e < nnz; e += nth)
        if (samp[rows[e]] == MARK) need[cols[e]] = MARK;
    __threadfence();
    grid.sync();

    // ---- P3: per-block inclusive scan of CHUNK need-flags ----
    int base = b * CHUNK;
    int i0   = base + t;
    int f    = 0;
    if (t < CHUNK && i0 < n && need[i0] == MARK) f = 1;
    if (t < CHUNK) sc[t] = f;
    __syncthreads();
    for (int off = 1; off < CHUNK; off <<= 1) {
        int add = 0;
        if (t < CHUNK && t >= off) add = sc[t - off];
        __syncthreads();
        if (t < CHUNK) sc[t] += add;
        __syncthreads();
    }
    if (t == 0) bsum[b] = sc[CHUNK - 1];
    __threadfence();
    grid.sync();

    // ---- P4: block 0 scans the CB block sums -> bpre (exclusive), Mptr ----
    if (b == 0) {
        int v[4];
        int s = 0;
        #pragma unroll
        for (int k = 0; k < 4; ++k) { v[k] = bsum[t * 4 + k]; s += v[k]; }
        ts[t] = s;
        __syncthreads();
        for (int off = 1; off < CT; off <<= 1) {
            int add = (t >= off) ? ts[t - off] : 0;
            __syncthreads();
            ts[t] += add;
            __syncthreads();
        }
        int run = ts[t] - s;
        #pragma unroll
        for (int k = 0; k < 4; ++k) { bpre[t * 4 + k] = run; run += v[k]; }
        if (t == CT - 1) Mptr[0] = ts[CT - 1];
    }
    __threadfence();
    grid.sync();

    // ---- P5: finalize idx / list (partials still live in sc + registers) ----
    int pre = bpre[b];
    if (t < CHUNK && i0 < n) {
        int excl = pre + sc[t] - f;
        if (f) { idx[i0] = excl; list[excl] = i0; }
        else idx[i0] = -1;
    }
}

// ---------------- S1: single-pass scatter into private per-(block,super) fragments ----------------
__global__ __launch_bounds__(512) void s1_k(
    const int* __restrict__ rows, const int* __restrict__ cols,
    const float* __restrict__ vals, const int* __restrict__ idx,
    int2* __restrict__ pairs1, int* __restrict__ scnt, int nnz)
{
    __shared__ int lcur[NSUP];
    int t = threadIdx.x;
    for (int i = t; i < NSUP; i += 512) lcur[i] = 0;
    __syncthreads();
    int b = blockIdx.x;
    int per = (nnz + S1B - 1) / S1B;
    int s = b * per;
    int e = min(nnz, s + per);
    for (int i = s + t; i < e; i += 512) {
        int ci = idx[rows[i]];
        if (ci < 0) continue;
        int sp = ci >> 11;
        int k = atomicAdd(&lcur[sp], 1);
        pairs1[(size_t)sp * (S1B * FRAG) + b * FRAG + k] =
            make_int2(((ci & 2047) << 18) | cols[i], __float_as_int(vals[i]));
    }
    __syncthreads();
    for (int i = t; i < NSUP; i += 512) scnt[i * S1B + b] = lcur[i];
}

// ---------------- S2: gather fragments of one super-part, scatter to fine buckets ----------------
__global__ __launch_bounds__(256) void s2_k(
    const int* __restrict__ scnt, const int2* __restrict__ pairs1,
    int* __restrict__ bcurP, int2* __restrict__ pairs)
{
    __shared__ int2 sbuf[S2CAP];
    __shared__ int fcnt[32], fcur[32], gb[32];
    int sp = blockIdx.x / BPS, part = blockIdx.x % BPS;
    int t = threadIdx.x;
    if (t < 32) { fcnt[t] = 0; fcur[t] = 0; }
    __syncthreads();
    int base = 0;
    for (int fi = 0; fi < FPB; ++fi) {
        int b = part * FPB + fi;
        int m = scnt[sp * S1B + b];
        const int2* src = &pairs1[(size_t)sp * (S1B * FRAG) + b * FRAG];
        for (int i = t; i < m; i += 256) {
            int2 p = src[i];
            sbuf[base + i] = p;
            atomicAdd(&fcnt[(p.x >> 18) >> 6], 1);
        }
        base += m;
    }
    __syncthreads();
    if (t < 32) {
        int c = fcnt[t];
        gb[t] = c ? atomicAdd(&bcurP[(sp * 32 + t) * CPAD], c) : 0;
    }
    __syncthreads();
    for (int i = t; i < base; i += 256) {
        int2 p = sbuf[i];
        int ris = p.x >> 18;
        int f = ris >> 6;
        int k = atomicAdd(&fcur[f], 1);
        pairs[gb[f] + k] = make_int2(((ris & 63) << 18) | (p.x & 0x3FFFF), p.y);
    }
}

// ---------------- Per-bucket LDS counting sort -> per-row ranges ----------------
__global__ __launch_bounds__(256) void sortb_k(
    const int* __restrict__ bcurP, int2* __restrict__ pairs,
    int* __restrict__ rp)
{
    __shared__ int2 buf[FCAP];
    __shared__ int cnt[64];
    __shared__ int cur[64];
    int b = blockIdx.x;
    int s = b * FCAP;
    int e = bcurP[b * CPAD];
    int m = e - s;
    int t = threadIdx.x;
    if (t < 64) cnt[t] = 0;
    __syncthreads();
    for (int i = t; i < m; i += 256) {
        int2 p = pairs[s + i];
        buf[i] = p;
        atomicAdd(&cnt[p.x >> 18], 1);
    }
    __syncthreads();
    if (t < 64) {
        int v = cnt[t];
        int incl = v;
        #pragma unroll
        for (int o = 1; o < 64; o <<= 1) {
            int u = __shfl_up(incl, o);
            if (t >= o) incl += u;
        }
        cur[t] = incl - v;
        rp[b * 65 + t] = s + incl - v;
        if (t == 63) rp[b * 65 + 64] = s + incl;
    }
    __syncthreads();
    for (int i = t; i < m; i += 256) {
        int2 p = buf[i];
        int dst = atomicAdd(&cur[p.x >> 18], 1);
        pairs[s + dst] = make_int2(p.x & 0x3FFFF, p.y);
    }
}

// ---------------- Fused layer-1: 32-row tile, 128 threads (2 waves x 16 rows x 4 passes) ----------------
// Measured floor for the random-gather phase (R1/R5/R11): ~56 µs, VGPR 48, 2.3 TB/s.
// 4 passes/wave required for the compiler's 8-deep load pipeline. Do not touch.
__global__ __launch_bounds__(128, 4) void fuse1_k(
    const int* __restrict__ rp, const int2* __restrict__ pairs,
    const float* __restrict__ x,
    const float* __restrict__ Wg, const float* __restrict__ bg,
    const float* __restrict__ Wb, const float* __restrict__ bb,
    float* __restrict__ out, const int* __restrict__ list,
    const int* __restrict__ Mptr)
{
    __shared__ __align__(16) float sAT[D][SPAD];
    __shared__ __align__(16) float sBT[D][SPAD];

    int nr = Mptr[0];
    int r0 = blockIdx.x * TILE1;
    if (r0 >= nr) return;

    int t    = threadIdx.x;
    int lane = t & 63;
    int wid  = t >> 6;          // 0..1
    int lq   = lane & 15;
    int qb   = lane & 48;

    for (int pass = 0; pass < 4; ++pass) {
        int rr  = wid * 16 + pass * 4 + (lane >> 4);  // 0..31
        int row = r0 + rr;
        int valid = row < nr;
        int s = 0, len = 0, er = 0;
        if (valid) {
            int rb = (row >> 6) * 65 + (row & 63);
            s = rp[rb];
            len = rp[rb + 1] - s;
            er = list[row];
        }
        int ml = len;
        ml = max(ml, __shfl_xor(ml, 16));
        ml = max(ml, __shfl_xor(ml, 32));

        float4 acc = make_float4(0.f, 0.f, 0.f, 0.f);
        for (int base = 0; base < ml; base += 16) {
            int2 p = make_int2(0, 0);
            int o = base + lq;
            if (o < len) p = pairs[s + o];
            int rem = len - base;
            rem = min(max(rem, 0), 16);
            int mr = rem;
            mr = max(mr, __shfl_xor(mr, 16));
            mr = max(mr, __shfl_xor(mr, 32));
            int cnt8 = (mr + 7) & ~7;
            for (int j = 0; j < cnt8; j += 8) {
                int c[8]; float v[8]; float4 f[8];
                #pragma unroll
                for (int q = 0; q < 8; ++q) {
                    c[q] = __shfl(p.x, qb | (j + q));
                    v[q] = __int_as_float(__shfl(p.y, qb | (j + q)));
                }
                #pragma unroll
                for (int q = 0; q < 8; ++q)
                    f[q] = *(const float4*)&x[(size_t)c[q] * D + lq * 4];
                #pragma unroll
                for (int q = 0; q < 8; ++q) {
                    acc.x = fmaf(v[q], f[q].x, acc.x);
                    acc.y = fmaf(v[q], f[q].y, acc.y);
                    acc.z = fmaf(v[q], f[q].z, acc.z);
                    acc.w = fmaf(v[q], f[q].w, acc.w);
                }
            }
        }
        float4 ev = make_float4(0.f, 0.f, 0.f, 0.f);
        if (valid) ev = *(const float4*)&x[(size_t)er * D + lq * 4];
        sAT[lq * 4 + 0][rr] = acc.x;
        sAT[lq * 4 + 1][rr] = acc.y;
        sAT[lq * 4 + 2][rr] = acc.z;
        sAT[lq * 4 + 3][rr] = acc.w;
        sBT[lq * 4 + 0][rr] = acc.x * ev.x;
        sBT[lq * 4 + 1][rr] = acc.y * ev.y;
        sBT[lq * 4 + 2][rr] = acc.z * ev.z;
        sBT[lq * 4 + 3][rr] = acc.w * ev.w;
    }
    __syncthreads();

    int tc = t & 15;
    int tr = t >> 4;            // 0..7
    float acc2[4][4] = {};
    #pragma unroll 4
    for (int k = 0; k < D; ++k) {
        float av[4] = {sAT[k][tr], sAT[k][tr + 8], sAT[k][tr + 16], sAT[k][tr + 24]};
        float bv[4] = {sBT[k][tr], sBT[k][tr + 8], sBT[k][tr + 16], sBT[k][tr + 24]};
        float4 g4 = *(const float4*)&Wg[k * D + tc * 4];
        float4 w4 = *(const float4*)&Wb[k * D + tc * 4];
        float gv[4] = {g4.x, g4.y, g4.z, g4.w};
        float wv[4] = {w4.x, w4.y, w4.z, w4.w};
        #pragma unroll
        for (int i = 0; i < 4; ++i)
            #pragma unroll
            for (int j = 0; j < 4; ++j)
                acc2[i][j] = fmaf(av[i], gv[j], fmaf(bv[i], wv[j], acc2[i][j]));
    }

    float4 bgv = *(const float4*)&bg[tc * 4];
    float4 bbv = *(const float4*)&bb[tc * 4];
    float bias[4] = {bgv.x + bbv.x, bgv.y + bbv.y, bgv.z + bbv.z, bgv.w + bbv.w};

    float vv[4][4];
    float ss[4] = {0.f, 0.f, 0.f, 0.f};
    #pragma unroll
    for (int i = 0; i < 4; ++i) {
        #pragma unroll
        for (int j = 0; j < 4; ++j) {
            float v = acc2[i][j] + bias[j];
            v = (v > 0.0f) ? v : 0.2f * v;
            vv[i][j] = v;
            ss[i] += v * v;
        }
    }
    #pragma unroll
    for (int i = 0; i < 4; ++i) {
        #pragma unroll
        for (int off = 1; off < 16; off <<= 1)
            ss[i] += __shfl_xor(ss[i], off);
    }
    #pragma unroll
    for (int i = 0; i < 4; ++i) {
        int row = r0 + tr + i * 8;
        if (row < nr) {
            int er2 = list[row];
            float inv = 1.0f / fmaxf(sqrtf(ss[i]), 1e-12f);
            float4 o = make_float4(vv[i][0] * inv, vv[i][1] * inv,
                                   vv[i][2] * inv, vv[i][3] * inv);
            *(float4*)&out[(size_t)er2 * D + tc * 4] = o;
        }
    }
}

// ---------------- Fused layer-2 (sampled rows): 16-row tiles for grid parallelism ----------------
__global__ __launch_bounds__(256, 4) void fuse2_k(
    const int* __restrict__ rp, const int2* __restrict__ pairs,
    const float* __restrict__ e1, const int* __restrict__ idx,
    const float* __restrict__ Wg, const float* __restrict__ bg,
    const float* __restrict__ Wb, const float* __restrict__ bb,
    float* __restrict__ out, const int* __restrict__ u,
    const int* __restrict__ it, int batch)
{
    __shared__ __align__(16) float sAT[D][SPAD2];
    __shared__ __align__(16) float sBT[D][SPAD2];

    int nr = 2 * batch;
    int r0 = blockIdx.x * 16;
    if (r0 >= nr) return;

    int t    = threadIdx.x;
    int lane = t & 63;
    int wid  = t >> 6;          // 0..3
    int lq   = lane & 15;
    int qb   = lane & 48;

    {
        int rr  = wid * 4 + (lane >> 4);
        int row = r0 + rr;
        int valid = row < nr;
        int s = 0, len = 0, n = 0;
        if (valid) {
            n = (row < batch) ? u[row] : N_USERS_C + it[row - batch];
            int cr = idx[n];
            int rb = (cr >> 6) * 65 + (cr & 63);
            s = rp[rb];
            len = rp[rb + 1] - s;
        }
        int ml = len;
        ml = max(ml, __shfl_xor(ml, 16));
        ml = max(ml, __shfl_xor(ml, 32));

        float4 acc = make_float4(0.f, 0.f, 0.f, 0.f);
        for (int base = 0; base < ml; base += 16) {
            int2 p = make_int2(0, 0);
            int o = base + lq;
            if (o < len) p = pairs[s + o];
            int rem = len - base;
            rem = min(max(rem, 0), 16);
            int mr = rem;
            mr = max(mr, __shfl_xor(mr, 16));
            mr = max(mr, __shfl_xor(mr, 32));
            int cnt8 = (mr + 7) & ~7;
            for (int j = 0; j < cnt8; j += 8) {
                int c[8]; float v[8]; float4 f[8];
                #pragma unroll
                for (int q = 0; q < 8; ++q) {
                    c[q] = __shfl(p.x, qb | (j + q));
                    v[q] = __int_as_float(__shfl(p.y, qb | (j + q)));
                }
                #pragma unroll
                for (int q = 0; q < 8; ++q)
                    f[q] = *(const float4*)&e1[(size_t)c[q] * D + lq * 4];
                #pragma unroll
                for (int q = 0; q < 8; ++q) {
                    acc.x = fmaf(v[q], f[q].x, acc.x);
                    acc.y = fmaf(v[q], f[q].y, acc.y);
                    acc.z = fmaf(v[q], f[q].z, acc.z);
                    acc.w = fmaf(v[q], f[q].w, acc.w);
                }
            }
        }
        float4 ev = make_float4(0.f, 0.f, 0.f, 0.f);
        if (valid) ev = *(const float4*)&e1[(size_t)n * D + lq * 4];
        sAT[lq * 4 + 0][rr] = acc.x;
        sAT[lq * 4 + 1][rr] = acc.y;
        sAT[lq * 4 + 2][rr] = acc.z;
        sAT[lq * 4 + 3][rr] = acc.w;
        sBT[lq * 4 + 0][rr] = acc.x * ev.x;
        sBT[lq * 4 + 1][rr] = acc.y * ev.y;
        sBT[lq * 4 + 2][rr] = acc.z * ev.z;
        sBT[lq * 4 + 3][rr] = acc.w * ev.w;
    }
    __syncthreads();

    int tc = t & 15;
    int tr = t >> 4;            // 0..15
    float acc2[4] = {};
    #pragma unroll 4
    for (int k = 0; k < D; ++k) {
        float a0 = sAT[k][tr];
        float b0 = sBT[k][tr];
        float4 g4 = *(const float4*)&Wg[k * D + tc * 4];
        float4 w4 = *(const float4*)&Wb[k * D + tc * 4];
        float gv[4] = {g4.x, g4.y, g4.z, g4.w};
        float wv[4] = {w4.x, w4.y, w4.z, w4.w};
        #pragma unroll
        for (int j = 0; j < 4; ++j)
            acc2[j] = fmaf(a0, gv[j], fmaf(b0, wv[j], acc2[j]));
    }

    float4 bgv = *(const float4*)&bg[tc * 4];
    float4 bbv = *(const float4*)&bb[tc * 4];
    float bias[4] = {bgv.x + bbv.x, bgv.y + bbv.y, bgv.z + bbv.z, bgv.w + bbv.w};

    float vv[4];
    float ss = 0.f;
    #pragma unroll
    for (int j = 0; j < 4; ++j) {
        float v = acc2[j] + bias[j];
        v = (v > 0.0f) ? v : 0.2f * v;
        vv[j] = v;
        ss += v * v;
    }
    #pragma unroll
    for (int off = 1; off < 16; off <<= 1)
        ss += __shfl_xor(ss, off);

    int row = r0 + tr;
    if (row < nr) {
        float inv = 1.0f / fmaxf(sqrtf(ss), 1e-12f);
        float4 o = make_float4(vv[0] * inv, vv[1] * inv, vv[2] * inv, vv[3] * inv);
        *(float4*)&out[(size_t)row * D + tc * 4] = o;
    }
}

// ---------------- Readout (e1 full node space: no idx) ----------------
__global__ __launch_bounds__(256) void gamma_k(
    const float* __restrict__ x, const float* __restrict__ e1,
    const float* __restrict__ e2c,
    const int* __restrict__ users, const int* __restrict__ items,
    float* __restrict__ gamma, int batch)
{
    int gtid = blockIdx.x * blockDim.x + threadIdx.x;
    int wave = gtid >> 6;
    int lane = threadIdx.x & 63;
    if (wave >= batch) return;
    size_t uu = (size_t)users[wave];
    size_t tt = (size_t)(N_USERS_C + items[wave]);
    float acc = x[uu * D + lane] * x[tt * D + lane]
              + e1[uu * D + lane] * e1[tt * D + lane]
              + e2c[(size_t)wave * D + lane] * e2c[(size_t)(batch + wave) * D + lane];
    #pragma unroll
    for (int off = 1; off < 64; off <<= 1) acc += __shfl_xor(acc, off);
    if (lane == 0) gamma[wave] = acc;
}

extern "C" void kernel_launch(void* const* d_in, const int* in_sizes, int n_in,
                              void* d_out, int out_size, void* d_ws, size_t ws_size,
                              hipStream_t stream) {
    const int*   rows  = (const int*)d_in[0];
    const int*   cols  = (const int*)d_in[1];
    const float* vals  = (const float*)d_in[2];
    const float* x     = (const float*)d_in[3];
    const int*   users = (const int*)d_in[4];
    const int*   items = (const int*)d_in[5];
    const float* Wg0 = (const float*)d_in[6];
    const float* bg0 = (const float*)d_in[7];
    const float* Wb0 = (const float*)d_in[8];
    const float* bb0 = (const float*)d_in[9];
    const float* Wg1 = (const float*)d_in[10];
    const float* bg1 = (const float*)d_in[11];
    const float* Wb1 = (const float*)d_in[12];
    const float* bb1 = (const float*)d_in[13];

    int nnz   = in_sizes[0];
    int batch = in_sizes[4];
    float* out = (float*)d_out;

    size_t emb = (size_t)N_NODES_C * D;
    float* A      = (float*)d_ws;                  // e1 [N x 64] FULL node space
    float* Sbuf   = A + emb;                       // pairs1 (build) / e2c (layer 2)
    int*   bcur   = (int*)(Sbuf + emb);            // NB*CPAD
    int*   rp     = bcur + NB * CPAD;              // NB*65 (+pad)
    int*   idx    = rp + NB * 65 + 2;              // [N]
    int*   list   = idx + N_NODES_C;               // [N]
    int*   bsum   = list + N_NODES_C;              // [1024]
    int*   bpre   = bsum + 1024;                   // [1024]
    int*   Mptr   = bpre + 1024;                   // [4]
    int*   scnt   = Mptr + 4;                      // [NSUP*S1B]
    unsigned char* need = (unsigned char*)(scnt + NSUP * S1B);   // [N]
    unsigned char* samp = need + N_NODES_C;                      // [N]
    int2*  pairs  = (int2*)(((size_t)(samp + N_NODES_C) + 15) & ~(size_t)15);  // NB*FCAP

    int2*  pairs1 = (int2*)Sbuf;                   // build-time only (36.4MB < 38.4MB)
    float* e2c    = Sbuf;                          // layer-2 output (pairs1 dead after s2)

    // --- front chain fused: mark + scan + compact (cooperative, 1 launch) ---
    {
        int n_nodes = N_NODES_C;
        void* cargs[] = {
            (void*)&users, (void*)&items, (void*)&rows, (void*)&cols,
            (void*)&samp, (void*)&need, (void*)&idx, (void*)&list,
            (void*)&bcur, (void*)&Mptr, (void*)&bsum, (void*)&bpre,
            (void*)&batch, (void*)&nnz, (void*)&n_nodes
        };
        hipLaunchCooperativeKernel((void*)front_k, dim3(CB), dim3(CT),
                                   cargs, 0, stream);
    }

    // --- bucket build: private fragments (LDS atomics only — R10 lesson: global
    //     per-edge atomics cost ~40 µs/million on gfx950) ---
    s1_k<<<S1B, 512, 0, stream>>>(rows, cols, vals, idx, pairs1, scnt, nnz);
    s2_k<<<NSUP * BPS, 256, 0, stream>>>(scnt, pairs1, bcur, pairs);
    sortb_k<<<NB, 256, 0, stream>>>(bcur, pairs, rp);

    // --- Layer 1: fused gather+transform, 32-row tiles, 128 threads (2 waves x 16 rows) ---
    fuse1_k<<<(N_NODES_C + TILE1 - 1) / TILE1, 128, 0, stream>>>(
        rp, pairs, x, Wg0, bg0, Wb0, bb0, A, list, Mptr);

    // --- Layer 2: fused gather+transform over 2*batch sampled rows, 16-row tiles ---
    fuse2_k<<<(2 * batch + 15) / 16, 256, 0, stream>>>(
        rp, pairs, A, idx, Wg1, bg1, Wb1, bb1, e2c, users, items, batch);

    // --- Readout ---
    gamma_k<<<(batch * 64 + 255) / 256, 256, 0, stream>>>(
        x, A, e2c, users, items, out, batch);
}

// Round 18
// 237.655 us; speedup vs baseline: 3.7985x; 3.7985x over previous
//
#include <hip/hip_runtime.h>

#define N_USERS_C 100000
#define N_NODES_C 150000
#define D 64
#define NB 2344              // ceil(150000/64) fine buckets (compact-row space)
#define NSUP 74              // ceil(150000/2048) super buckets
#define CPAD 16              // global cursor padding: 1 int per 64B line
#define TILE1 32             // fuse1 rows per block
#define SPAD 33              // fuse1 transposed-tile row stride (2-way banks, free)
#define SPAD2 17             // fuse2 transposed-tile row stride (2-way)
#define FCAP 1536            // fixed fine-bucket capacity (mean ~1030)
#define S1B 256              // s1 blocks
#define FRAG 240             // per-(block,super) fragment capacity (mean 128, +10 sigma)
#define S2CAP 2560           // s2 per-block staging capacity
#define BPS 16               // blocks per super in s2
#define FPB (S1B / BPS)      // fragments per s2 block = 16
#define NSCAN 147            // ceil(150000/1024)
#define MARK 1               // "marked" byte; ws poison is 0xAA so no zeroing needed

// ---------------- Needed-set marking (no memset: poison 0xAA != MARK) ----------------
// R12 lesson: cooperative grid.sync costs ~160 µs/sync on MI355X (cross-XCD barrier);
// kernel launches ARE the cheap grid barrier. Keep these as separate kernels.
__global__ __launch_bounds__(256) void mark1_k(
    const int* __restrict__ u, const int* __restrict__ it,
    unsigned char* __restrict__ samp, unsigned char* __restrict__ need, int batch)
{
    int i = blockIdx.x * blockDim.x + threadIdx.x;
    if (i >= 2 * batch) return;
    int n = (i < batch) ? u[i] : N_USERS_C + it[i - batch];
    samp[n] = MARK;
    need[n] = MARK;
}

__global__ __launch_bounds__(256) void mark2_k(
    const int* __restrict__ rows, const int* __restrict__ cols,
    const unsigned char* __restrict__ samp, unsigned char* __restrict__ need, int nnz)
{
    int gtid = blockIdx.x * blockDim.x + threadIdx.x;
    int stride = gridDim.x * blockDim.x;
    for (int e = gtid; e < nnz; e += stride)
        if (samp[rows[e]] == MARK) need[cols[e]] = MARK;
}

// ---------------- scan1: per-block scan of need flags ----------------
__global__ __launch_bounds__(1024) void scan1_k(
    const unsigned char* __restrict__ need, int* __restrict__ part,
    int* __restrict__ bsum, int n)
{
    __shared__ int wsum[16];
    int i = blockIdx.x * 1024 + threadIdx.x;
    int lane = threadIdx.x & 63, wid = threadIdx.x >> 6;
    int v = (i < n && need[i] == MARK) ? 1 : 0;
    int incl = v;
    #pragma unroll
    for (int off = 1; off < 64; off <<= 1) {
        int t = __shfl_up(incl, off);
        if (lane >= off) incl += t;
    }
    if (lane == 63) wsum[wid] = incl;
    __syncthreads();
    int woff = 0;
    for (int w = 0; w < wid; ++w) woff += wsum[w];
    if (i < n) part[i] = woff + incl - v;
    if (threadIdx.x == 1023) bsum[blockIdx.x] = woff + incl;
}

// ---------------- scanB: local prefix of bsum + finalize idx/list + cursors + Mptr ----------------
__global__ __launch_bounds__(256) void scanB_k(
    const int* __restrict__ bsum, int* __restrict__ idx,
    const unsigned char* __restrict__ need, int* __restrict__ list,
    int* __restrict__ bcur, int* __restrict__ Mptr, int n)
{
    __shared__ int pre[NSCAN + 1];
    __shared__ int raw[NSCAN];
    int t = threadIdx.x;
    if (t < NSCAN) raw[t] = bsum[t];
    __syncthreads();
    if (t == 0) {
        int run = 0;
        for (int k = 0; k < NSCAN; ++k) { pre[k] = run; run += raw[k]; }
        pre[NSCAN] = run;
    }
    __syncthreads();
    int i = blockIdx.x * blockDim.x + t;
    if (i < NB) bcur[i * CPAD] = i * FCAP;
    if (blockIdx.x == 0 && t == 0) Mptr[0] = pre[NSCAN];
    if (i >= n) return;
    int val = idx[i] + pre[i >> 10];
    if (need[i] == MARK) { idx[i] = val; list[val] = i; }
    else idx[i] = -1;
}

// ---------------- S1: single-pass scatter into private per-(block,super) fragments ----------------
__global__ __launch_bounds__(512) void s1_k(
    const int* __restrict__ rows, const int* __restrict__ cols,
    const float* __restrict__ vals, const int* __restrict__ idx,
    int2* __restrict__ pairs1, int* __restrict__ scnt, int nnz)
{
    __shared__ int lcur[NSUP];
    int t = threadIdx.x;
    for (int i = t; i < NSUP; i += 512) lcur[i] = 0;
    __syncthreads();
    int b = blockIdx.x;
    int per = (nnz + S1B - 1) / S1B;
    int s = b * per;
    int e = min(nnz, s + per);
    for (int i = s + t; i < e; i += 512) {
        int ci = idx[rows[i]];
        if (ci < 0) continue;
        int sp = ci >> 11;
        int k = atomicAdd(&lcur[sp], 1);
        pairs1[(size_t)sp * (S1B * FRAG) + b * FRAG + k] =
            make_int2(((ci & 2047) << 18) | cols[i], __float_as_int(vals[i]));
    }
    __syncthreads();
    for (int i = t; i < NSUP; i += 512) scnt[i * S1B + b] = lcur[i];
}

// ---------------- S2: gather fragments of one super-part, scatter to fine buckets ----------------
__global__ __launch_bounds__(256) void s2_k(
    const int* __restrict__ scnt, const int2* __restrict__ pairs1,
    int* __restrict__ bcurP, int2* __restrict__ pairs)
{
    __shared__ int2 sbuf[S2CAP];
    __shared__ int fcnt[32], fcur[32], gb[32];
    int sp = blockIdx.x / BPS, part = blockIdx.x % BPS;
    int t = threadIdx.x;
    if (t < 32) { fcnt[t] = 0; fcur[t] = 0; }
    __syncthreads();
    int base = 0;
    for (int fi = 0; fi < FPB; ++fi) {
        int b = part * FPB + fi;
        int m = scnt[sp * S1B + b];
        const int2* src = &pairs1[(size_t)sp * (S1B * FRAG) + b * FRAG];
        for (int i = t; i < m; i += 256) {
            int2 p = src[i];
            sbuf[base + i] = p;
            atomicAdd(&fcnt[(p.x >> 18) >> 6], 1);
        }
        base += m;
    }
    __syncthreads();
    if (t < 32) {
        int c = fcnt[t];
        gb[t] = c ? atomicAdd(&bcurP[(sp * 32 + t) * CPAD], c) : 0;
    }
    __syncthreads();
    for (int i = t; i < base; i += 256) {
        int2 p = sbuf[i];
        int ris = p.x >> 18;
        int f = ris >> 6;
        int k = atomicAdd(&fcur[f], 1);
        pairs[gb[f] + k] = make_int2(((ris & 63) << 18) | (p.x & 0x3FFFF), p.y);
    }
}

// ---------------- Per-bucket LDS counting sort -> per-row ranges ----------------
__global__ __launch_bounds__(256) void sortb_k(
    const int* __restrict__ bcurP, int2* __restrict__ pairs,
    int* __restrict__ rp)
{
    __shared__ int2 buf[FCAP];
    __shared__ int cnt[64];
    __shared__ int cur[64];
    int b = blockIdx.x;
    int s = b * FCAP;
    int e = bcurP[b * CPAD];
    int m = e - s;
    int t = threadIdx.x;
    if (t < 64) cnt[t] = 0;
    __syncthreads();
    for (int i = t; i < m; i += 256) {
        int2 p = pairs[s + i];
        buf[i] = p;
        atomicAdd(&cnt[p.x >> 18], 1);
    }
    __syncthreads();
    if (t < 64) {
        int v = cnt[t];
        int incl = v;
        #pragma unroll
        for (int o = 1; o < 64; o <<= 1) {
            int u = __shfl_up(incl, o);
            if (t >= o) incl += u;
        }
        cur[t] = incl - v;
        rp[b * 65 + t] = s + incl - v;
        if (t == 63) rp[b * 65 + 64] = s + incl;
    }
    __syncthreads();
    for (int i = t; i < m; i += 256) {
        int2 p = buf[i];
        int dst = atomicAdd(&cur[p.x >> 18], 1);
        pairs[s + dst] = make_int2(p.x & 0x3FFFF, p.y);
    }
}

// ---------------- Fused layer-1: 32-row tile, 128 threads (2 waves x 16 rows x 4 passes) ----------------
// Measured floor for the random-gather phase (R1/R5/R11): ~56 µs, VGPR 48, 2.3 TB/s.
// 4 passes/wave required for the compiler's 8-deep load pipeline. Do not touch.
__global__ __launch_bounds__(128, 4) void fuse1_k(
    const int* __restrict__ rp, const int2* __restrict__ pairs,
    const float* __restrict__ x,
    const float* __restrict__ Wg, const float* __restrict__ bg,
    const float* __restrict__ Wb, const float* __restrict__ bb,
    float* __restrict__ out, const int* __restrict__ list,
    const int* __restrict__ Mptr)
{
    __shared__ __align__(16) float sAT[D][SPAD];
    __shared__ __align__(16) float sBT[D][SPAD];

    int nr = Mptr[0];
    int r0 = blockIdx.x * TILE1;
    if (r0 >= nr) return;

    int t    = threadIdx.x;
    int lane = t & 63;
    int wid  = t >> 6;          // 0..1
    int lq   = lane & 15;
    int qb   = lane & 48;

    for (int pass = 0; pass < 4; ++pass) {
        int rr  = wid * 16 + pass * 4 + (lane >> 4);  // 0..31
        int row = r0 + rr;
        int valid = row < nr;
        int s = 0, len = 0, er = 0;
        if (valid) {
            int rb = (row >> 6) * 65 + (row & 63);
            s = rp[rb];
            len = rp[rb + 1] - s;
            er = list[row];
        }
        int ml = len;
        ml = max(ml, __shfl_xor(ml, 16));
        ml = max(ml, __shfl_xor(ml, 32));

        float4 acc = make_float4(0.f, 0.f, 0.f, 0.f);
        for (int base = 0; base < ml; base += 16) {
            int2 p = make_int2(0, 0);
            int o = base + lq;
            if (o < len) p = pairs[s + o];
            int rem = len - base;
            rem = min(max(rem, 0), 16);
            int mr = rem;
            mr = max(mr, __shfl_xor(mr, 16));
            mr = max(mr, __shfl_xor(mr, 32));
            int cnt8 = (mr + 7) & ~7;
            for (int j = 0; j < cnt8; j += 8) {
                int c[8]; float v[8]; float4 f[8];
                #pragma unroll
                for (int q = 0; q < 8; ++q) {
                    c[q] = __shfl(p.x, qb | (j + q));
                    v[q] = __int_as_float(__shfl(p.y, qb | (j + q)));
                }
                #pragma unroll
                for (int q = 0; q < 8; ++q)
                    f[q] = *(const float4*)&x[(size_t)c[q] * D + lq * 4];
                #pragma unroll
                for (int q = 0; q < 8; ++q) {
                    acc.x = fmaf(v[q], f[q].x, acc.x);
                    acc.y = fmaf(v[q], f[q].y, acc.y);
                    acc.z = fmaf(v[q], f[q].z, acc.z);
                    acc.w = fmaf(v[q], f[q].w, acc.w);
                }
            }
        }
        float4 ev = make_float4(0.f, 0.f, 0.f, 0.f);
        if (valid) ev = *(const float4*)&x[(size_t)er * D + lq * 4];
        sAT[lq * 4 + 0][rr] = acc.x;
        sAT[lq * 4 + 1][rr] = acc.y;
        sAT[lq * 4 + 2][rr] = acc.z;
        sAT[lq * 4 + 3][rr] = acc.w;
        sBT[lq * 4 + 0][rr] = acc.x * ev.x;
        sBT[lq * 4 + 1][rr] = acc.y * ev.y;
        sBT[lq * 4 + 2][rr] = acc.z * ev.z;
        sBT[lq * 4 + 3][rr] = acc.w * ev.w;
    }
    __syncthreads();

    int tc = t & 15;
    int tr = t >> 4;            // 0..7
    float acc2[4][4] = {};
    #pragma unroll 4
    for (int k = 0; k < D; ++k) {
        float av[4] = {sAT[k][tr], sAT[k][tr + 8], sAT[k][tr + 16], sAT[k][tr + 24]};
        float bv[4] = {sBT[k][tr], sBT[k][tr + 8], sBT[k][tr + 16], sBT[k][tr + 24]};
        float4 g4 = *(const float4*)&Wg[k * D + tc * 4];
        float4 w4 = *(const float4*)&Wb[k * D + tc * 4];
        float gv[4] = {g4.x, g4.y, g4.z, g4.w};
        float wv[4] = {w4.x, w4.y, w4.z, w4.w};
        #pragma unroll
        for (int i = 0; i < 4; ++i)
            #pragma unroll
            for (int j = 0; j < 4; ++j)
                acc2[i][j] = fmaf(av[i], gv[j], fmaf(bv[i], wv[j], acc2[i][j]));
    }

    float4 bgv = *(const float4*)&bg[tc * 4];
    float4 bbv = *(const float4*)&bb[tc * 4];
    float bias[4] = {bgv.x + bbv.x, bgv.y + bbv.y, bgv.z + bbv.z, bgv.w + bbv.w};

    float vv[4][4];
    float ss[4] = {0.f, 0.f, 0.f, 0.f};
    #pragma unroll
    for (int i = 0; i < 4; ++i) {
        #pragma unroll
        for (int j = 0; j < 4; ++j) {
            float v = acc2[i][j] + bias[j];
            v = (v > 0.0f) ? v : 0.2f * v;
            vv[i][j] = v;
            ss[i] += v * v;
        }
    }
    #pragma unroll
    for (int i = 0; i < 4; ++i) {
        #pragma unroll
        for (int off = 1; off < 16; off <<= 1)
            ss[i] += __shfl_xor(ss[i], off);
    }
    #pragma unroll
    for (int i = 0; i < 4; ++i) {
        int row = r0 + tr + i * 8;
        if (row < nr) {
            int er2 = list[row];
            float inv = 1.0f / fmaxf(sqrtf(ss[i]), 1e-12f);
            float4 o = make_float4(vv[i][0] * inv, vv[i][1] * inv,
                                   vv[i][2] * inv, vv[i][3] * inv);
            *(float4*)&out[(size_t)er2 * D + tc * 4] = o;
        }
    }
}

// ---------------- Fused layer-2 + gamma: 8 pairs/block (16 rows: 8 user + 8 item) ----------------
// Normalized outputs stay in LDS; readout dot computed in-block (32 lanes/pair,
// 2 cols/lane, shfl_xor tree). R15 crash fix: sN writer is lq==0 (one per rr),
// NOT lq==0 && qb==0 (which left 12/16 sN entries uninitialized -> OOB gather).
__global__ __launch_bounds__(256, 4) void fuse2g_k(
    const int* __restrict__ rp, const int2* __restrict__ pairs,
    const float* __restrict__ e1, const int* __restrict__ idx,
    const float* __restrict__ Wg, const float* __restrict__ bg,
    const float* __restrict__ Wb, const float* __restrict__ bb,
    const float* __restrict__ x,
    const int* __restrict__ u, const int* __restrict__ it,
    float* __restrict__ gamma, int batch)
{
    __shared__ __align__(16) float sAT[D][SPAD2];
    __shared__ __align__(16) float sBT[D][SPAD2];
    __shared__ __align__(16) float sOUT[16][68];
    __shared__ int sN[16];

    int p0 = blockIdx.x * 8;
    if (p0 >= batch) return;

    int t    = threadIdx.x;
    int lane = t & 63;
    int wid  = t >> 6;          // 0..3
    int lq   = lane & 15;
    int qb   = lane & 48;

    {
        int rr  = wid * 4 + (lane >> 4);          // 0..15
        int pr  = p0 + (rr & 7);
        int valid = pr < batch;
        int s = 0, len = 0, n = 0;
        if (valid) {
            n = (rr < 8) ? u[pr] : N_USERS_C + it[pr];
            if (lq == 0) sN[rr] = n;              // one writer per row (lane == qb)
            int cr = idx[n];
            int rb = (cr >> 6) * 65 + (cr & 63);
            s = rp[rb];
            len = rp[rb + 1] - s;
        }
        int ml = len;
        ml = max(ml, __shfl_xor(ml, 16));
        ml = max(ml, __shfl_xor(ml, 32));

        float4 acc = make_float4(0.f, 0.f, 0.f, 0.f);
        for (int base = 0; base < ml; base += 16) {
            int2 p = make_int2(0, 0);
            int o = base + lq;
            if (o < len) p = pairs[s + o];
            int rem = len - base;
            rem = min(max(rem, 0), 16);
            int mr = rem;
            mr = max(mr, __shfl_xor(mr, 16));
            mr = max(mr, __shfl_xor(mr, 32));
            int cnt8 = (mr + 7) & ~7;
            for (int j = 0; j < cnt8; j += 8) {
                int c[8]; float v[8]; float4 f[8];
                #pragma unroll
                for (int q = 0; q < 8; ++q) {
                    c[q] = __shfl(p.x, qb | (j + q));
                    v[q] = __int_as_float(__shfl(p.y, qb | (j + q)));
                }
                #pragma unroll
                for (int q = 0; q < 8; ++q)
                    f[q] = *(const float4*)&e1[(size_t)c[q] * D + lq * 4];
                #pragma unroll
                for (int q = 0; q < 8; ++q) {
                    acc.x = fmaf(v[q], f[q].x, acc.x);
                    acc.y = fmaf(v[q], f[q].y, acc.y);
                    acc.z = fmaf(v[q], f[q].z, acc.z);
                    acc.w = fmaf(v[q], f[q].w, acc.w);
                }
            }
        }
        float4 ev = make_float4(0.f, 0.f, 0.f, 0.f);
        if (valid) ev = *(const float4*)&e1[(size_t)n * D + lq * 4];
        sAT[lq * 4 + 0][rr] = acc.x;
        sAT[lq * 4 + 1][rr] = acc.y;
        sAT[lq * 4 + 2][rr] = acc.z;
        sAT[lq * 4 + 3][rr] = acc.w;
        sBT[lq * 4 + 0][rr] = acc.x * ev.x;
        sBT[lq * 4 + 1][rr] = acc.y * ev.y;
        sBT[lq * 4 + 2][rr] = acc.z * ev.z;
        sBT[lq * 4 + 3][rr] = acc.w * ev.w;
    }
    __syncthreads();

    // ---- transform: 256 threads, each 1 row x 4 cols; normalized output -> LDS ----
    {
        int tc = t & 15;
        int tr = t >> 4;            // 0..15
        float acc2[4] = {};
        #pragma unroll 4
        for (int k = 0; k < D; ++k) {
            float a0 = sAT[k][tr];
            float b0 = sBT[k][tr];
            float4 g4 = *(const float4*)&Wg[k * D + tc * 4];
            float4 w4 = *(const float4*)&Wb[k * D + tc * 4];
            float gv[4] = {g4.x, g4.y, g4.z, g4.w};
            float wv[4] = {w4.x, w4.y, w4.z, w4.w};
            #pragma unroll
            for (int j = 0; j < 4; ++j)
                acc2[j] = fmaf(a0, gv[j], fmaf(b0, wv[j], acc2[j]));
        }

        float4 bgv = *(const float4*)&bg[tc * 4];
        float4 bbv = *(const float4*)&bb[tc * 4];
        float bias[4] = {bgv.x + bbv.x, bgv.y + bbv.y, bgv.z + bbv.z, bgv.w + bbv.w};

        float vv[4];
        float ss = 0.f;
        #pragma unroll
        for (int j = 0; j < 4; ++j) {
            float v = acc2[j] + bias[j];
            v = (v > 0.0f) ? v : 0.2f * v;
            vv[j] = v;
            ss += v * v;
        }
        #pragma unroll
        for (int off = 1; off < 16; off <<= 1)
            ss += __shfl_xor(ss, off);

        float inv = 1.0f / fmaxf(sqrtf(ss), 1e-12f);
        #pragma unroll
        for (int j = 0; j < 4; ++j)
            sOUT[tr][tc * 4 + j] = vv[j] * inv;
    }
    __syncthreads();

    // ---- gamma: pair = t>>5 (0..7), 32 lanes/pair, 2 cols/lane ----
    {
        int pair = t >> 5;          // 0..7
        int l    = t & 31;
        int pr   = p0 + pair;
        if (pr < batch) {
            size_t uu = (size_t)sN[pair];
            size_t tt = (size_t)sN[pair + 8];
            float acc =
                x[uu * D + l]  * x[tt * D + l]  + x[uu * D + l + 32]  * x[tt * D + l + 32] +
                e1[uu * D + l] * e1[tt * D + l] + e1[uu * D + l + 32] * e1[tt * D + l + 32] +
                sOUT[pair][l]  * sOUT[pair + 8][l] +
                sOUT[pair][l + 32] * sOUT[pair + 8][l + 32];
            #pragma unroll
            for (int off = 1; off < 32; off <<= 1)
                acc += __shfl_xor(acc, off);
            if (l == 0) gamma[pr] = acc;
        }
    }
}

extern "C" void kernel_launch(void* const* d_in, const int* in_sizes, int n_in,
                              void* d_out, int out_size, void* d_ws, size_t ws_size,
                              hipStream_t stream) {
    const int*   rows  = (const int*)d_in[0];
    const int*   cols  = (const int*)d_in[1];
    const float* vals  = (const float*)d_in[2];
    const float* x     = (const float*)d_in[3];
    const int*   users = (const int*)d_in[4];
    const int*   items = (const int*)d_in[5];
    const float* Wg0 = (const float*)d_in[6];
    const float* bg0 = (const float*)d_in[7];
    const float* Wb0 = (const float*)d_in[8];
    const float* bb0 = (const float*)d_in[9];
    const float* Wg1 = (const float*)d_in[10];
    const float* bg1 = (const float*)d_in[11];
    const float* Wb1 = (const float*)d_in[12];
    const float* bb1 = (const float*)d_in[13];

    int nnz   = in_sizes[0];
    int batch = in_sizes[4];
    float* out = (float*)d_out;

    size_t emb = (size_t)N_NODES_C * D;
    float* A      = (float*)d_ws;                  // e1 [N x 64] FULL node space
    float* Sbuf   = A + emb;                       // pairs1 (build-time only)
    int*   bcur   = (int*)(Sbuf + emb);            // NB*CPAD
    int*   rp     = bcur + NB * CPAD;              // NB*65 (+pad)
    int*   idx    = rp + NB * 65 + 2;              // [N]
    int*   list   = idx + N_NODES_C;               // [N]
    int*   bsum   = list + N_NODES_C;              // [1024]
    int*   Mptr   = bsum + 1024;                   // [4]
    int*   scnt   = Mptr + 4;                      // [NSUP*S1B]
    unsigned char* need = (unsigned char*)(scnt + NSUP * S1B);   // [N]
    unsigned char* samp = need + N_NODES_C;                      // [N]
    int2*  pairs  = (int2*)(((size_t)(samp + N_NODES_C) + 15) & ~(size_t)15);  // NB*FCAP

    int2*  pairs1 = (int2*)Sbuf;                   // build-time only (36.4MB < 38.4MB)

    // --- needed-set mark + compact (no memset: poison-as-unmarked) ---
    mark1_k<<<(2 * batch + 255) / 256, 256, 0, stream>>>(users, items, samp, need, batch);
    mark2_k<<<1024, 256, 0, stream>>>(rows, cols, samp, need, nnz);
    scan1_k<<<NSCAN, 1024, 0, stream>>>(need, idx, bsum, N_NODES_C);
    scanB_k<<<(N_NODES_C + 255) / 256, 256, 0, stream>>>(bsum, idx, need, list, bcur, Mptr, N_NODES_C);

    // --- bucket build: private fragments (LDS atomics only — R10 lesson: global
    //     per-edge atomics cost ~40 µs/million on gfx950) ---
    s1_k<<<S1B, 512, 0, stream>>>(rows, cols, vals, idx, pairs1, scnt, nnz);
    s2_k<<<NSUP * BPS, 256, 0, stream>>>(scnt, pairs1, bcur, pairs);
    sortb_k<<<NB, 256, 0, stream>>>(bcur, pairs, rp);

    // --- Layer 1: fused gather+transform, 32-row tiles, 128 threads (2 waves x 16 rows) ---
    fuse1_k<<<(N_NODES_C + TILE1 - 1) / TILE1, 128, 0, stream>>>(
        rp, pairs, x, Wg0, bg0, Wb0, bb0, A, list, Mptr);

    // --- Layer 2 + readout fused: 8 pairs/block ---
    fuse2g_k<<<(batch + 7) / 8, 256, 0, stream>>>(
        rp, pairs, A, idx, Wg1, bg1, Wb1, bb1, x, users, items, out, batch);
}